// Round 10
// baseline (295.497 us; speedup 1.0000x reference)
//
#include <hip/hip_runtime.h>

typedef _Float16 f16;
typedef f16 f16x8 __attribute__((ext_vector_type(8)));
typedef f16 f16x4 __attribute__((ext_vector_type(4)));
typedef float f32x4 __attribute__((ext_vector_type(4)));

#define GLD_LDS16(g, l) __builtin_amdgcn_global_load_lds( \
    (const __attribute__((address_space(1))) void*)(g),   \
    (__attribute__((address_space(3))) void*)(l), 16, 0, 0)

__device__ __forceinline__ void bar() {
    asm volatile("" ::: "memory");
    __builtin_amdgcn_s_barrier();
    asm volatile("" ::: "memory");
}
#define WAIT_VM(n) { asm volatile("s_waitcnt vmcnt(" #n ")" ::: "memory"); \
                     __builtin_amdgcn_sched_barrier(0); }
#define LGKM(n)    { asm volatile("s_waitcnt lgkmcnt(" #n ")" ::: "memory"); \
                     __builtin_amdgcn_sched_barrier(0); }

// ---------------------------------------------------------------------------
// f32 -> f16 flat cast, 2048 elems/block
__global__ __launch_bounds__(256) void cast_f32_f16(const float* __restrict__ x,
                                                    f16* __restrict__ xh) {
    long i = ((long)blockIdx.x * 256 + threadIdx.x) * 8;
    float4 a = *(const float4*)&x[i];
    float4 b = *(const float4*)&x[i + 4];
    f16x8 v;
    v[0] = (f16)a.x; v[1] = (f16)a.y; v[2] = (f16)a.z; v[3] = (f16)a.w;
    v[4] = (f16)b.x; v[5] = (f16)b.y; v[6] = (f16)b.z; v[7] = (f16)b.w;
    *(f16x8*)&xh[i] = v;
}

// cast + transpose one 1024x1024 f32 matrix -> f16 transposed (64x64 tiles)
__global__ __launch_bounds__(256) void cast_transpose_1k(const float* __restrict__ Wi,
                                                         f16* __restrict__ WTi) {
    __shared__ float tile[64][65];
    const int d0 = blockIdx.y * 64;
    const int o0 = blockIdx.x * 64;
    const int t = threadIdx.x;
#pragma unroll
    for (int j = 0; j < 4; ++j) {
        int idx = t + j * 256;
        int r = idx >> 4;
        int c4 = (idx & 15) * 4;
        float4 v = *(const float4*)&Wi[(long)(d0 + r) * 1024 + o0 + c4];
        tile[r][c4 + 0] = v.x; tile[r][c4 + 1] = v.y;
        tile[r][c4 + 2] = v.z; tile[r][c4 + 3] = v.w;
    }
    __syncthreads();
#pragma unroll
    for (int j = 0; j < 2; ++j) {
        int idx = t + j * 256;
        int ol = idx >> 3;
        int c8 = (idx & 7) * 8;
        f16x8 v;
#pragma unroll
        for (int e = 0; e < 8; ++e) v[e] = (f16)tile[c8 + e][ol];
        *(f16x8*)&WTi[(long)(o0 + ol) * 1024 + d0 + c8] = v;
    }
}

// ---------------------------------------------------------------------------
// small 128x128-tile 2-phase gemm for Mp (1024^3): C fp16 = A * B^T
__global__ __launch_bounds__(256, 2)
void gemm_mp(const f16* __restrict__ A, const f16* __restrict__ B,
             f16* __restrict__ C) {
    __shared__ f16x8 ls[2][2][4][128];
    const int tid = threadIdx.x;
    const int lane = tid & 63;
    const int wave = tid >> 6;
    const int wm = wave >> 1;
    const int wn = wave & 1;
    const long m_base = (long)blockIdx.y * 128;
    const long n_base = (long)blockIdx.x * 128;

    const int i1 = tid + 256;
    const int kb0 = tid >> 7, r0 = tid & 127;
    const int kb1 = i1 >> 7, r1 = i1 & 127;
    const f16* gA0 = A + (m_base + r0) * 1024L + kb0 * 8;
    const f16* gA1 = A + (m_base + r1) * 1024L + kb1 * 8;
    const f16* gB0 = B + (n_base + r0) * 1024L + kb0 * 8;
    const f16* gB1 = B + (n_base + r1) * 1024L + kb1 * 8;

    auto stage = [&](int buf, int k0) {
        GLD_LDS16(gA0 + k0, &ls[buf][0][kb0][r0]);
        GLD_LDS16(gA1 + k0, &ls[buf][0][kb1][r1]);
        GLD_LDS16(gB0 + k0, &ls[buf][1][kb0][r0]);
        GLD_LDS16(gB1 + k0, &ls[buf][1][kb1][r1]);
    };

    f32x4 acc[4][4];
#pragma unroll
    for (int i = 0; i < 4; ++i)
#pragma unroll
        for (int j = 0; j < 4; ++j) acc[i][j] = (f32x4){0.f, 0.f, 0.f, 0.f};

    stage(0, 0);
    WAIT_VM(0);
    bar();
    int cur = 0;
    const int kb = lane >> 4;
    const int fr = lane & 15;
    for (int t = 0; t < 32; ++t) {
        if (t + 1 < 32) stage(cur ^ 1, (t + 1) << 5);
        f16x8 af[4], bf[4];
#pragma unroll
        for (int mi = 0; mi < 4; ++mi) af[mi] = ls[cur][0][kb][wm * 64 + mi * 16 + fr];
#pragma unroll
        for (int ni = 0; ni < 4; ++ni) bf[ni] = ls[cur][1][kb][wn * 64 + ni * 16 + fr];
#pragma unroll
        for (int mi = 0; mi < 4; ++mi)
#pragma unroll
            for (int ni = 0; ni < 4; ++ni)
                acc[mi][ni] = __builtin_amdgcn_mfma_f32_16x16x32_f16(
                    af[mi], bf[ni], acc[mi][ni], 0, 0, 0);
        WAIT_VM(0);
        bar();
        cur ^= 1;
    }
    const int rq = lane >> 4;
#pragma unroll
    for (int mi = 0; mi < 4; ++mi) {
        long r0_ = m_base + wm * 64 + mi * 16 + rq * 4;
#pragma unroll
        for (int ni = 0; ni < 4; ++ni) {
            long c = n_base + wn * 64 + ni * 16 + fr;
#pragma unroll
            for (int j = 0; j < 4; ++j)
                C[(r0_ + j) * 1024L + c] = (f16)acc[mi][ni][j];
        }
    }
}

// ---------------------------------------------------------------------------
// 256x256 tile, BK=64, 8-phase schedule (T1+T2+T3+T4+T5), 512 threads = 8
// waves (2 m-waves x 4 n-waves), per-wave output 128x64, 16x16x32 MFMA.
// LDS 128 KiB ring (+4 KiB wsum region for MODE 0, at smem+131072 — OUTSIDE
// the ring so the next-tile prefetch can never race the reduction).
//
// TILES = tiles per block, advancing in TDIR (0 = n, 1 = m). m-direction
// tiling keeps the B-panel hot in L2 and the A-tiles private (R8 showed
// n-direction tiling on a streaming B doubles A re-fetch).
//
// XCD mapping: dispatch round-robins global block id over 8 XCDs, so
// xcd = (bx + Gx*by) & 7 when Gx*Gy % 8 == 0 (z preserved). Each XCD gets
// an RW x RH rectangle of (bx, by) tiles -> per-XCD fetch = RH A-panels +
// RW B-panels (minimized at RW ~ RH) instead of a 1-D row/column.
//
// MODE 0: scores: C fp16 = exp2(acc*scale - 5.77078016) (= exp(S/8 - 4));
//         fused per-block row sums -> psum[(z*2048+row)*8 + bx].
// MODE 2: PV: C f32 = acc * dinv[z*2048 + row]
// MODE 4: TV split: cols [0,1024) -> T [16384][1024] at Cv;
//         cols [1024,2048) -> V^T [8][1024][2048] at Cv + 64 MiB.
template <int MODE, int TILES, int TDIR, int RW, int RH>
__global__ __launch_bounds__(512, 2)
void gemm256(const f16* __restrict__ A, const f16* __restrict__ B,
             void* __restrict__ Cv, const float* __restrict__ dinv,
             float* __restrict__ psum,
             int lda, int ldb, int K,
             long sA, long sB, long sC, int ldc, float scale) {
    extern __shared__ __align__(16) char smem[];
    const int tid = threadIdx.x;
    const int lane = tid & 63;
    const int wave = tid >> 6;
    const int wm = wave >> 2;          // 0..1
    const int wn = wave & 3;           // 0..3
    const int z = blockIdx.z;

    // ---- T1: rectangular XCD-aware block mapping
    const int o_ = blockIdx.x + gridDim.x * blockIdx.y;
    const int xcd = o_ & 7;
    const int idx = o_ >> 3;
    const int nrbx = gridDim.x / RW;   // rects per row of grid
    const int bx_s = (xcd % nrbx) * RW + (idx % RW);
    const int by_s = (xcd / nrbx) * RH + (idx / RW);

    const int tile_m0 = (TDIR == 1) ? by_s * TILES : by_s;
    const int tile_n0 = (TDIR == 0) ? bx_s * TILES : bx_s;

    const f16* Ab = A + (long)z * sA;
    const f16* Bb = B + (long)z * sB;

    // ---- staging geometry: 1024 chunks of 16B per half-tile, 2 per thread
    const int c_r0 = tid >> 3;                             // rows 0..63 (li=0)
    const int c_col = ((tid & 7) * 8) ^ ((c_r0 & 7) << 3); // inverse-swizzled col
    long oA0 = ((long)tile_m0 * 256 + c_r0) * (long)lda + c_col;
    long oA1 = oA0 + 64L * lda;                            // li=1: rows 64..127
    long oB0 = ((long)tile_n0 * 256 + c_r0) * (long)ldb + c_col;
    long oB1 = oB0 + 64L * ldb;

#define ST_A0(bf_, kt_) { long k0_ = (long)(kt_) * 64; \
    char* d_ = smem + (bf_) * 65536 + tid * 16; \
    GLD_LDS16(Ab + oA0 + k0_, d_); GLD_LDS16(Ab + oA1 + k0_, d_ + 8192); }
#define ST_A1(bf_, kt_) { long k0_ = (long)(kt_) * 64 + 128L * lda; \
    char* d_ = smem + (bf_) * 65536 + 16384 + tid * 16; \
    GLD_LDS16(Ab + oA0 + k0_, d_); GLD_LDS16(Ab + oA1 + k0_, d_ + 8192); }
#define ST_B0(bf_, kt_) { long k0_ = (long)(kt_) * 64; \
    char* d_ = smem + (bf_) * 65536 + 32768 + tid * 16; \
    GLD_LDS16(Bb + oB0 + k0_, d_); GLD_LDS16(Bb + oB1 + k0_, d_ + 8192); }
#define ST_B1(bf_, kt_) { long k0_ = (long)(kt_) * 64 + 128L * ldb; \
    char* d_ = smem + (bf_) * 65536 + 49152 + tid * 16; \
    GLD_LDS16(Bb + oB0 + k0_, d_); GLD_LDS16(Bb + oB1 + k0_, d_ + 8192); }

    // ---- fragment read offsets (swizzled; verified conflict-free)
    const int fr = lane & 15;
    const int rq = lane >> 4;
    const int cs0 = (rq * 16) ^ ((lane & 7) << 4);
    const int cs1 = cs0 ^ 64;
    const int aoff = wm * 16384 + fr * 128;
    const int boff = 32768 + (wn >> 1) * 16384 + (wn & 1) * 8192 + fr * 128;

    const int NT = K >> 6;   // K-tiles of 64 (NT >= 16 for our shapes)

    // ---- prologue (tile 0): K0 all 4 halves, then K1 B0,B1,A0
    ST_B0(0, 0); ST_B1(0, 0); ST_A0(0, 0); ST_A1(0, 0);
    WAIT_VM(4);
    ST_B0(1, 1); ST_B1(1, 1); ST_A0(1, 1);
    WAIT_VM(6);
    bar();

    for (int tt = 0; tt < TILES; ++tt) {
        const long m_base = (long)((TDIR == 1) ? tile_m0 + tt : tile_m0) * 256;
        const long n_base = (long)((TDIR == 0) ? tile_n0 + tt : tile_n0) * 256;

        f32x4 acc[8][4];
#pragma unroll
        for (int i = 0; i < 8; ++i)
#pragma unroll
            for (int j = 0; j < 4; ++j) acc[i][j] = (f32x4){0.f, 0.f, 0.f, 0.f};

        for (int j = 0; j < NT; ++j) {
            char* bufb = smem + (j & 1) * 65536;
            const char* Ap = bufb + aoff;
            const char* Bp = bufb + boff;
            f16x8 af[4][2], bf[4][2];

            // ---------- phase 1: af(8) -> bf01(4) -> bf23(4); lgkm(4) covers
            // exactly {af, bf01} (DS returns retire in order).
#pragma unroll
            for (int i = 0; i < 4; ++i) {
                af[i][0] = *(const f16x8*)(Ap + i * 2048 + cs0);
                af[i][1] = *(const f16x8*)(Ap + i * 2048 + cs1);
            }
            __builtin_amdgcn_sched_barrier(0);
#pragma unroll
            for (int ni = 0; ni < 2; ++ni) {
                bf[ni][0] = *(const f16x8*)(Bp + ni * 2048 + cs0);
                bf[ni][1] = *(const f16x8*)(Bp + ni * 2048 + cs1);
            }
            __builtin_amdgcn_sched_barrier(0);
#pragma unroll
            for (int ni = 2; ni < 4; ++ni) {
                bf[ni][0] = *(const f16x8*)(Bp + ni * 2048 + cs0);
                bf[ni][1] = *(const f16x8*)(Bp + ni * 2048 + cs1);
            }
            if (j + 1 < NT) ST_A1((j + 1) & 1, j + 1);
            bar();
            LGKM(4);
            __builtin_amdgcn_s_setprio(1);
#pragma unroll
            for (int ks = 0; ks < 2; ++ks)
#pragma unroll
                for (int i = 0; i < 4; ++i)
#pragma unroll
                    for (int n = 0; n < 2; ++n)
                        acc[i][n] = __builtin_amdgcn_mfma_f32_16x16x32_f16(
                            af[i][ks], bf[n][ks], acc[i][n], 0, 0, 0);
            __builtin_amdgcn_s_setprio(0);
            bar();

            // ---------- phase 2
            LGKM(0);   // bf23 retired -> safe to overwrite B0 slot
            if (j + 2 < NT) ST_B0(j & 1, j + 2);
            bar();
            __builtin_amdgcn_s_setprio(1);
#pragma unroll
            for (int ks = 0; ks < 2; ++ks)
#pragma unroll
                for (int i = 0; i < 4; ++i)
#pragma unroll
                    for (int n = 0; n < 2; ++n)
                        acc[i][2 + n] = __builtin_amdgcn_mfma_f32_16x16x32_f16(
                            af[i][ks], bf[2 + n][ks], acc[i][2 + n], 0, 0, 0);
            __builtin_amdgcn_s_setprio(0);
            bar();

            // ---------- phase 3
#pragma unroll
            for (int i = 0; i < 4; ++i) {
                af[i][0] = *(const f16x8*)(Ap + (4 + i) * 2048 + cs0);
                af[i][1] = *(const f16x8*)(Ap + (4 + i) * 2048 + cs1);
            }
            if (j + 2 < NT) ST_B1(j & 1, j + 2);
            bar();
            LGKM(0);
            __builtin_amdgcn_s_setprio(1);
#pragma unroll
            for (int ks = 0; ks < 2; ++ks)
#pragma unroll
                for (int i = 0; i < 4; ++i)
#pragma unroll
                    for (int n = 0; n < 2; ++n)
                        acc[4 + i][n] = __builtin_amdgcn_mfma_f32_16x16x32_f16(
                            af[i][ks], bf[n][ks], acc[4 + i][n], 0, 0, 0);
            __builtin_amdgcn_s_setprio(0);
            bar();

            // ---------- phase 4
            if (j + 2 < NT) {
                ST_A0(j & 1, j + 2);
                WAIT_VM(6);
            } else if (j + 1 < NT) {
                WAIT_VM(0);
            }
            bar();
            __builtin_amdgcn_s_setprio(1);
#pragma unroll
            for (int ks = 0; ks < 2; ++ks)
#pragma unroll
                for (int i = 0; i < 4; ++i)
#pragma unroll
                    for (int n = 0; n < 2; ++n)
                        acc[4 + i][2 + n] = __builtin_amdgcn_mfma_f32_16x16x32_f16(
                            af[i][ks], bf[2 + n][ks], acc[4 + i][2 + n], 0, 0, 0);
            __builtin_amdgcn_s_setprio(0);
            bar();
        }

        // ---- next-tile prologue issued BEFORE epilogue (latency hidden
        // under stores). All ring slots free here: tail guards drained vmcnt
        // and the final bar retired all ds_reads. MODE 0's wsum lives at
        // smem+131072, outside the ring, so no overlap with these DMAs.
        if (tt + 1 < TILES) {
            if (TDIR == 0) {
                oB0 = ((long)(tile_n0 + tt + 1) * 256 + c_r0) * (long)ldb + c_col;
                oB1 = oB0 + 64L * ldb;
            } else {
                oA0 = ((long)(tile_m0 + tt + 1) * 256 + c_r0) * (long)lda + c_col;
                oA1 = oA0 + 64L * lda;
            }
            ST_B0(0, 0); ST_B1(0, 0); ST_A0(0, 0); ST_A1(0, 0);
            ST_B0(1, 1); ST_B1(1, 1); ST_A0(1, 1);
        }

        // ---- epilogue: C/D layout col = lane&15, row = (lane>>4)*4 + jj
        if constexpr (MODE == 0) {
            f16* C = (f16*)Cv + (long)z * sC;
            float p[8][4];
#pragma unroll
            for (int mi = 0; mi < 8; ++mi)
#pragma unroll
                for (int jj = 0; jj < 4; ++jj) p[mi][jj] = 0.f;
#pragma unroll
            for (int mi = 0; mi < 8; ++mi) {
                long r0 = m_base + wm * 128 + mi * 16 + rq * 4;
#pragma unroll
                for (int ni = 0; ni < 4; ++ni) {
                    long c = n_base + wn * 64 + ni * 16 + fr;
#pragma unroll
                    for (int jj = 0; jj < 4; ++jj) {
                        // exp(S/8 - 4) = exp2(acc*scale - 5.77078016),
                        // scale pre-folded with log2(e)
                        float e = exp2f(acc[mi][ni][jj] * scale - 5.77078016f);
                        C[(r0 + jj) * (long)ldc + c] = (f16)e;
                        p[mi][jj] += e;
                    }
                }
            }
            // reduce over the 16 col-lanes sharing each row
#pragma unroll
            for (int mi = 0; mi < 8; ++mi)
#pragma unroll
                for (int jj = 0; jj < 4; ++jj)
#pragma unroll
                    for (int o = 8; o; o >>= 1)
                        p[mi][jj] += __shfl_xor(p[mi][jj], o);
            float* wsum = (float*)(smem + 131072);   // outside the ring
            if (fr == 0) {
#pragma unroll
                for (int mi = 0; mi < 8; ++mi)
#pragma unroll
                    for (int jj = 0; jj < 4; ++jj)
                        wsum[wn * 256 + wm * 128 + mi * 16 + rq * 4 + jj] = p[mi][jj];
            }
            bar();
            if (tid < 256) {
                float s = wsum[tid] + wsum[256 + tid] + wsum[512 + tid] + wsum[768 + tid];
                psum[((long)z * 2048 + m_base + tid) * 8 + (int)(n_base >> 8)] = s;
            }
        } else {
#pragma unroll
            for (int mi = 0; mi < 8; ++mi) {
                long r0 = m_base + wm * 128 + mi * 16 + rq * 4;
#pragma unroll
                for (int ni = 0; ni < 4; ++ni) {
                    long c = n_base + wn * 64 + ni * 16 + fr;
                    if constexpr (MODE == 2) {
                        float* C = (float*)Cv + (long)z * sC;
#pragma unroll
                        for (int jj = 0; jj < 4; ++jj)
                            C[(r0 + jj) * (long)ldc + c] =
                                acc[mi][ni][jj] * dinv[(long)z * 2048 + r0 + jj];
                    } else {  // MODE 4: TV split
                        if (c < 1024) {
                            f16* T = (f16*)Cv;
#pragma unroll
                            for (int jj = 0; jj < 4; ++jj)
                                T[(r0 + jj) * 1024L + c] = (f16)acc[mi][ni][jj];
                        } else {
                            f16* VT = (f16*)((char*)Cv + 67108864);
                            long o = c - 1024;
                            long b = r0 >> 11;
                            long s = r0 & 2047;
                            f16x4 v;
#pragma unroll
                            for (int jj = 0; jj < 4; ++jj) v[jj] = (f16)acc[mi][ni][jj];
                            *(f16x4*)&VT[b * 2097152L + o * 2048L + s] = v;
                        }
                    }
                }
            }
        }

        if (tt + 1 < TILES) {
            WAIT_VM(6);   // FIFO: all K0 loads (oldest) resident; <=6 newest remain
            bar();
        }
    }
#undef ST_A0
#undef ST_A1
#undef ST_B0
#undef ST_B1
}

// ---------------------------------------------------------------------------
// dinv[row] = 1 / sum_{k<8} psum[row*8+k]   (16384 rows)
__global__ __launch_bounds__(256) void reduce_dinv(const float* __restrict__ psum,
                                                   float* __restrict__ dinv) {
    int r = blockIdx.x * 256 + threadIdx.x;
    float4 a = *(const float4*)&psum[(long)r * 8];
    float4 b = *(const float4*)&psum[(long)r * 8 + 4];
    dinv[r] = 1.f / (a.x + a.y + a.z + a.w + b.x + b.y + b.z + b.w);
}

// ---------------------------------------------------------------------------
extern "C" void kernel_launch(void* const* d_in, const int* in_sizes, int n_in,
                              void* d_out, int out_size, void* d_ws, size_t ws_size,
                              hipStream_t stream) {
    const float* x = (const float*)d_in[0];    // [8,2048,1024]
    const float* w = (const float*)d_in[1];    // [3,1024,1024]
    float* out = (float*)d_out;                // [8,2048,1024] f32
    char* ws = (char*)d_ws;

    // workspace layout (bytes), 160 MiB total:
    //   [0,32M)    th: T = x*(WqWk^T)  [16384][1024] f16   (dead after scores)
    //   [32M,64M)  xh: x f16           [16384][1024]       (dead after scores)
    //   [64M,96M)  vt: V^T             [8][1024][2048] f16 (until PV)
    //   [96M,160M) sp: E = exp(S/8-4)  [8][2048][2048] f16
    //     pre-scores this region temporarily holds whq/whk/bTV (all dead
    //     before scores writes sp).
    f16* th  = (f16*)(ws + 0);
    f16* xh  = (f16*)(ws + 33554432);
    f16* vt  = (f16*)(ws + 67108864);
    char* spB = ws + 100663296;
    f16* whq = (f16*)(spB);
    f16* whk = (f16*)(spB + 2097152);
    f16* bTV = (f16*)(spB + 4194304);     // [2048][1024] f16: Mp ; WvT
    f16* sp  = (f16*)(spB);
    float* dinv = (float*)(ws + 0);       // overlays dead th after scores
    float* psum = (float*)d_out;          // 512 KB scratch, overwritten by PV

    // 1) casts: w[0],w[1] -> f16 flat (whq,whk contiguous); Wv -> WvT; x -> xh
    cast_f32_f16<<<1024, 256, 0, stream>>>(w, whq);
    cast_transpose_1k<<<dim3(16, 16), 256, 0, stream>>>(w + 2097152, bTV + 1048576);
    cast_f32_f16<<<8192, 256, 0, stream>>>(x, xh);

    // 2) Mp[i][j] = sum_o Wk[i][o]*Wq[j][o]  (B-operand rows of (WqWk^T))
    gemm_mp<<<dim3(8, 8), 256, 0, stream>>>(whk, whq, bTV);

    // 3) [T | V^T] = x * [Mp ; WvT]^T — n-TILES=2 (B-panel bTV L2-resident);
    //    RW=4,RH=8 reproduces the validated R9 mapping exactly.
    gemm256<4, 2, 0, 4, 8><<<dim3(4, 64, 1), 512, 131072, stream>>>(
        xh, bTV, ws, nullptr, nullptr, 1024, 1024, 1024, 0L, 0L, 0L, 0, 1.0f);

    // 4) E = exp2(T*x^T*0.18034 - 5.7708) -> sp; fused row sums -> psum.
    //    m-TILES=2 (A-tiles private, B-panel L2-hot), 2x2 XCD rectangles,
    //    256 blocks = one full GPU round. 132 KB dyn-LDS (ring + wsum).
    gemm256<0, 2, 1, 2, 2><<<dim3(8, 4, 8), 512, 135168, stream>>>(
        th, xh, sp, nullptr, psum, 1024, 1024, 1024,
        2097152L, 2097152L, 4194304L, 2048, 0.125f * 1.44269504f);

    // 5) dinv = 1 / rowsum
    reduce_dinv<<<64, 256, 0, stream>>>(psum, dinv);

    // 6) out = (E * V) * dinv — 2x2 XCD rectangles.
    gemm256<2, 1, 1, 2, 2><<<dim3(4, 8, 8), 512, 131072, stream>>>(
        sp, vt, out, dinv, nullptr, 2048, 2048, 2048,
        4194304L, 2097152L, 2097152L, 1024, 1.0f);
}

// Round 11
// 286.688 us; speedup vs baseline: 1.0307x; 1.0307x over previous
//
#include <hip/hip_runtime.h>

typedef _Float16 f16;
typedef f16 f16x8 __attribute__((ext_vector_type(8)));
typedef f16 f16x4 __attribute__((ext_vector_type(4)));
typedef float f32x4 __attribute__((ext_vector_type(4)));

#define GLD_LDS16(g, l) __builtin_amdgcn_global_load_lds( \
    (const __attribute__((address_space(1))) void*)(g),   \
    (__attribute__((address_space(3))) void*)(l), 16, 0, 0)

__device__ __forceinline__ void bar() {
    asm volatile("" ::: "memory");
    __builtin_amdgcn_s_barrier();
    asm volatile("" ::: "memory");
}
#define WAIT_VM(n) { asm volatile("s_waitcnt vmcnt(" #n ")" ::: "memory"); \
                     __builtin_amdgcn_sched_barrier(0); }
#define LGKM(n)    { asm volatile("s_waitcnt lgkmcnt(" #n ")" ::: "memory"); \
                     __builtin_amdgcn_sched_barrier(0); }

// ---------------------------------------------------------------------------
// merged input prep (one dispatch):
//   blocks [0,8192):    cast x f32 -> xh f16 (2048 elems/block)
//   blocks [8192,9216): cast w[0],w[1] f32 -> whqk f16 flat
//   blocks [9216,9472): cast+transpose w[2] -> wvT (64x64 tiles)
__global__ __launch_bounds__(256) void prep_inputs(const float* __restrict__ x,
                                                   const float* __restrict__ w,
                                                   f16* __restrict__ xh,
                                                   f16* __restrict__ whqk,
                                                   f16* __restrict__ wvT) {
    __shared__ float tile[64][65];
    const int bid = blockIdx.x;
    const int t = threadIdx.x;
    if (bid < 9216) {
        const float* src = (bid < 8192) ? x : w;
        f16* dst = (bid < 8192) ? xh : whqk;
        long base = (bid < 8192) ? (long)bid : (long)(bid - 8192);
        long i = (base * 256 + t) * 8;
        float4 a = *(const float4*)&src[i];
        float4 b = *(const float4*)&src[i + 4];
        f16x8 v;
        v[0] = (f16)a.x; v[1] = (f16)a.y; v[2] = (f16)a.z; v[3] = (f16)a.w;
        v[4] = (f16)b.x; v[5] = (f16)b.y; v[6] = (f16)b.z; v[7] = (f16)b.w;
        *(f16x8*)&dst[i] = v;
    } else {
        const int tb = bid - 9216;
        const int d0 = (tb >> 4) * 64;
        const int o0 = (tb & 15) * 64;
        const float* Wi = w + 2097152;   // w[2] = Wv
#pragma unroll
        for (int j = 0; j < 4; ++j) {
            int idx = t + j * 256;
            int r = idx >> 4;
            int c4 = (idx & 15) * 4;
            float4 v = *(const float4*)&Wi[(long)(d0 + r) * 1024 + o0 + c4];
            tile[r][c4 + 0] = v.x; tile[r][c4 + 1] = v.y;
            tile[r][c4 + 2] = v.z; tile[r][c4 + 3] = v.w;
        }
        __syncthreads();
#pragma unroll
        for (int j = 0; j < 2; ++j) {
            int idx = t + j * 256;
            int ol = idx >> 3;
            int c8 = (idx & 7) * 8;
            f16x8 v;
#pragma unroll
            for (int e = 0; e < 8; ++e) v[e] = (f16)tile[c8 + e][ol];
            *(f16x8*)&wvT[(long)(o0 + ol) * 1024 + d0 + c8] = v;
        }
    }
}

// ---------------------------------------------------------------------------
// small 128x128-tile 2-phase gemm for Mp (1024^3): C fp16 = A * B^T
__global__ __launch_bounds__(256, 2)
void gemm_mp(const f16* __restrict__ A, const f16* __restrict__ B,
             f16* __restrict__ C) {
    __shared__ f16x8 ls[2][2][4][128];
    const int tid = threadIdx.x;
    const int lane = tid & 63;
    const int wave = tid >> 6;
    const int wm = wave >> 1;
    const int wn = wave & 1;
    const long m_base = (long)blockIdx.y * 128;
    const long n_base = (long)blockIdx.x * 128;

    const int i1 = tid + 256;
    const int kb0 = tid >> 7, r0 = tid & 127;
    const int kb1 = i1 >> 7, r1 = i1 & 127;
    const f16* gA0 = A + (m_base + r0) * 1024L + kb0 * 8;
    const f16* gA1 = A + (m_base + r1) * 1024L + kb1 * 8;
    const f16* gB0 = B + (n_base + r0) * 1024L + kb0 * 8;
    const f16* gB1 = B + (n_base + r1) * 1024L + kb1 * 8;

    auto stage = [&](int buf, int k0) {
        GLD_LDS16(gA0 + k0, &ls[buf][0][kb0][r0]);
        GLD_LDS16(gA1 + k0, &ls[buf][0][kb1][r1]);
        GLD_LDS16(gB0 + k0, &ls[buf][1][kb0][r0]);
        GLD_LDS16(gB1 + k0, &ls[buf][1][kb1][r1]);
    };

    f32x4 acc[4][4];
#pragma unroll
    for (int i = 0; i < 4; ++i)
#pragma unroll
        for (int j = 0; j < 4; ++j) acc[i][j] = (f32x4){0.f, 0.f, 0.f, 0.f};

    stage(0, 0);
    WAIT_VM(0);
    bar();
    int cur = 0;
    const int kb = lane >> 4;
    const int fr = lane & 15;
    for (int t = 0; t < 32; ++t) {
        if (t + 1 < 32) stage(cur ^ 1, (t + 1) << 5);
        f16x8 af[4], bf[4];
#pragma unroll
        for (int mi = 0; mi < 4; ++mi) af[mi] = ls[cur][0][kb][wm * 64 + mi * 16 + fr];
#pragma unroll
        for (int ni = 0; ni < 4; ++ni) bf[ni] = ls[cur][1][kb][wn * 64 + ni * 16 + fr];
#pragma unroll
        for (int mi = 0; mi < 4; ++mi)
#pragma unroll
            for (int ni = 0; ni < 4; ++ni)
                acc[mi][ni] = __builtin_amdgcn_mfma_f32_16x16x32_f16(
                    af[mi], bf[ni], acc[mi][ni], 0, 0, 0);
        WAIT_VM(0);
        bar();
        cur ^= 1;
    }
    const int rq = lane >> 4;
#pragma unroll
    for (int mi = 0; mi < 4; ++mi) {
        long r0_ = m_base + wm * 64 + mi * 16 + rq * 4;
#pragma unroll
        for (int ni = 0; ni < 4; ++ni) {
            long c = n_base + wn * 64 + ni * 16 + fr;
#pragma unroll
            for (int j = 0; j < 4; ++j)
                C[(r0_ + j) * 1024L + c] = (f16)acc[mi][ni][j];
        }
    }
}

// ---------------------------------------------------------------------------
// 256x256 tile, BK=64, 8-phase schedule (T1+T2+T3+T4+T5), 512 threads = 8
// waves (2 m-waves x 4 n-waves), per-wave output 128x64, 16x16x32 MFMA.
// LDS 128 KiB ring (+4 KiB wsum region for MODE 0 at smem+131072, outside
// the ring so next-tile prefetch DMA can never race the reduction).
//
// TILES = tiles per block, advancing in TDIR (0 = n, 1 = m).
// XCD mapping: xcd = global block id & 7; each XCD gets an RW x RH
// rectangle of (bx,by) tiles. Per-GEMM mappings are the measured winners:
//   TV:     RW=4,RH=8 (== validated R9 1-D mapping)
//   scores: m-TILES=2, 2x2 rect (R10: 88.5us, FETCH 136MB)
//   PV:     RW=4,RH=1 (== R9 1-D mapping: by=xcd; R10's 2x2 regressed ~4us)
//
// MODE 0: scores: C fp16 = exp2(acc*scale - 5.77078016) (= exp(S/8 - 4));
//         fused per-block row sums -> psum[(z*2048+row)*8 + bx].
// MODE 2: PV: C f32 = acc * dinv[z*2048 + row]
// MODE 4: TV split: cols [0,1024) -> T [16384][1024] at Cv;
//         cols [1024,2048) -> V^T [8][1024][2048] at Cv + 64 MiB.
template <int MODE, int TILES, int TDIR, int RW, int RH>
__global__ __launch_bounds__(512, 2)
void gemm256(const f16* __restrict__ A, const f16* __restrict__ B,
             void* __restrict__ Cv, const float* __restrict__ dinv,
             float* __restrict__ psum,
             int lda, int ldb, int K,
             long sA, long sB, long sC, int ldc, float scale) {
    extern __shared__ __align__(16) char smem[];
    const int tid = threadIdx.x;
    const int lane = tid & 63;
    const int wave = tid >> 6;
    const int wm = wave >> 2;          // 0..1
    const int wn = wave & 3;           // 0..3
    const int z = blockIdx.z;

    // ---- T1: rectangular XCD-aware block mapping
    const int o_ = blockIdx.x + gridDim.x * blockIdx.y;
    const int xcd = o_ & 7;
    const int idx = o_ >> 3;
    const int nrbx = gridDim.x / RW;   // rects per row of grid
    const int bx_s = (xcd % nrbx) * RW + (idx % RW);
    const int by_s = (xcd / nrbx) * RH + (idx / RW);

    const int tile_m0 = (TDIR == 1) ? by_s * TILES : by_s;
    const int tile_n0 = (TDIR == 0) ? bx_s * TILES : bx_s;

    const f16* Ab = A + (long)z * sA;
    const f16* Bb = B + (long)z * sB;

    // ---- staging geometry: 1024 chunks of 16B per half-tile, 2 per thread
    const int c_r0 = tid >> 3;                             // rows 0..63 (li=0)
    const int c_col = ((tid & 7) * 8) ^ ((c_r0 & 7) << 3); // inverse-swizzled col
    long oA0 = ((long)tile_m0 * 256 + c_r0) * (long)lda + c_col;
    long oA1 = oA0 + 64L * lda;                            // li=1: rows 64..127
    long oB0 = ((long)tile_n0 * 256 + c_r0) * (long)ldb + c_col;
    long oB1 = oB0 + 64L * ldb;

#define ST_A0(bf_, kt_) { long k0_ = (long)(kt_) * 64; \
    char* d_ = smem + (bf_) * 65536 + tid * 16; \
    GLD_LDS16(Ab + oA0 + k0_, d_); GLD_LDS16(Ab + oA1 + k0_, d_ + 8192); }
#define ST_A1(bf_, kt_) { long k0_ = (long)(kt_) * 64 + 128L * lda; \
    char* d_ = smem + (bf_) * 65536 + 16384 + tid * 16; \
    GLD_LDS16(Ab + oA0 + k0_, d_); GLD_LDS16(Ab + oA1 + k0_, d_ + 8192); }
#define ST_B0(bf_, kt_) { long k0_ = (long)(kt_) * 64; \
    char* d_ = smem + (bf_) * 65536 + 32768 + tid * 16; \
    GLD_LDS16(Bb + oB0 + k0_, d_); GLD_LDS16(Bb + oB1 + k0_, d_ + 8192); }
#define ST_B1(bf_, kt_) { long k0_ = (long)(kt_) * 64 + 128L * ldb; \
    char* d_ = smem + (bf_) * 65536 + 49152 + tid * 16; \
    GLD_LDS16(Bb + oB0 + k0_, d_); GLD_LDS16(Bb + oB1 + k0_, d_ + 8192); }

    // ---- fragment read offsets (swizzled; verified conflict-free)
    const int fr = lane & 15;
    const int rq = lane >> 4;
    const int cs0 = (rq * 16) ^ ((lane & 7) << 4);
    const int cs1 = cs0 ^ 64;
    const int aoff = wm * 16384 + fr * 128;
    const int boff = 32768 + (wn >> 1) * 16384 + (wn & 1) * 8192 + fr * 128;

    const int NT = K >> 6;   // K-tiles of 64 (NT >= 16 for our shapes)

    // ---- prologue (tile 0): K0 all 4 halves, then K1 B0,B1,A0
    ST_B0(0, 0); ST_B1(0, 0); ST_A0(0, 0); ST_A1(0, 0);
    WAIT_VM(4);
    ST_B0(1, 1); ST_B1(1, 1); ST_A0(1, 1);
    WAIT_VM(6);
    bar();

    for (int tt = 0; tt < TILES; ++tt) {
        const long m_base = (long)((TDIR == 1) ? tile_m0 + tt : tile_m0) * 256;
        const long n_base = (long)((TDIR == 0) ? tile_n0 + tt : tile_n0) * 256;

        f32x4 acc[8][4];
#pragma unroll
        for (int i = 0; i < 8; ++i)
#pragma unroll
            for (int j = 0; j < 4; ++j) acc[i][j] = (f32x4){0.f, 0.f, 0.f, 0.f};

        for (int j = 0; j < NT; ++j) {
            char* bufb = smem + (j & 1) * 65536;
            const char* Ap = bufb + aoff;
            const char* Bp = bufb + boff;
            f16x8 af[4][2], bf[4][2];

            // ---------- phase 1: af(8) -> bf01(4) -> bf23(4); lgkm(4) covers
            // exactly {af, bf01} (DS returns retire in order).
#pragma unroll
            for (int i = 0; i < 4; ++i) {
                af[i][0] = *(const f16x8*)(Ap + i * 2048 + cs0);
                af[i][1] = *(const f16x8*)(Ap + i * 2048 + cs1);
            }
            __builtin_amdgcn_sched_barrier(0);
#pragma unroll
            for (int ni = 0; ni < 2; ++ni) {
                bf[ni][0] = *(const f16x8*)(Bp + ni * 2048 + cs0);
                bf[ni][1] = *(const f16x8*)(Bp + ni * 2048 + cs1);
            }
            __builtin_amdgcn_sched_barrier(0);
#pragma unroll
            for (int ni = 2; ni < 4; ++ni) {
                bf[ni][0] = *(const f16x8*)(Bp + ni * 2048 + cs0);
                bf[ni][1] = *(const f16x8*)(Bp + ni * 2048 + cs1);
            }
            if (j + 1 < NT) ST_A1((j + 1) & 1, j + 1);
            bar();
            LGKM(4);
            __builtin_amdgcn_s_setprio(1);
#pragma unroll
            for (int ks = 0; ks < 2; ++ks)
#pragma unroll
                for (int i = 0; i < 4; ++i)
#pragma unroll
                    for (int n = 0; n < 2; ++n)
                        acc[i][n] = __builtin_amdgcn_mfma_f32_16x16x32_f16(
                            af[i][ks], bf[n][ks], acc[i][n], 0, 0, 0);
            __builtin_amdgcn_s_setprio(0);
            bar();

            // ---------- phase 2
            LGKM(0);   // bf23 retired -> safe to overwrite B0 slot
            if (j + 2 < NT) ST_B0(j & 1, j + 2);
            bar();
            __builtin_amdgcn_s_setprio(1);
#pragma unroll
            for (int ks = 0; ks < 2; ++ks)
#pragma unroll
                for (int i = 0; i < 4; ++i)
#pragma unroll
                    for (int n = 0; n < 2; ++n)
                        acc[i][2 + n] = __builtin_amdgcn_mfma_f32_16x16x32_f16(
                            af[i][ks], bf[2 + n][ks], acc[i][2 + n], 0, 0, 0);
            __builtin_amdgcn_s_setprio(0);
            bar();

            // ---------- phase 3
#pragma unroll
            for (int i = 0; i < 4; ++i) {
                af[i][0] = *(const f16x8*)(Ap + (4 + i) * 2048 + cs0);
                af[i][1] = *(const f16x8*)(Ap + (4 + i) * 2048 + cs1);
            }
            if (j + 2 < NT) ST_B1(j & 1, j + 2);
            bar();
            LGKM(0);
            __builtin_amdgcn_s_setprio(1);
#pragma unroll
            for (int ks = 0; ks < 2; ++ks)
#pragma unroll
                for (int i = 0; i < 4; ++i)
#pragma unroll
                    for (int n = 0; n < 2; ++n)
                        acc[4 + i][n] = __builtin_amdgcn_mfma_f32_16x16x32_f16(
                            af[i][ks], bf[n][ks], acc[4 + i][n], 0, 0, 0);
            __builtin_amdgcn_s_setprio(0);
            bar();

            // ---------- phase 4
            if (j + 2 < NT) {
                ST_A0(j & 1, j + 2);
                WAIT_VM(6);
            } else if (j + 1 < NT) {
                WAIT_VM(0);
            }
            bar();
            __builtin_amdgcn_s_setprio(1);
#pragma unroll
            for (int ks = 0; ks < 2; ++ks)
#pragma unroll
                for (int i = 0; i < 4; ++i)
#pragma unroll
                    for (int n = 0; n < 2; ++n)
                        acc[4 + i][2 + n] = __builtin_amdgcn_mfma_f32_16x16x32_f16(
                            af[i][ks], bf[2 + n][ks], acc[4 + i][2 + n], 0, 0, 0);
            __builtin_amdgcn_s_setprio(0);
            bar();
        }

        // ---- next-tile prologue issued BEFORE epilogue (latency hidden
        // under stores). All ring slots free here: tail guards drained vmcnt
        // and the final bar retired all ds_reads. MODE 0's wsum lives at
        // smem+131072, outside the ring, so no overlap with these DMAs.
        if (tt + 1 < TILES) {
            if (TDIR == 0) {
                oB0 = ((long)(tile_n0 + tt + 1) * 256 + c_r0) * (long)ldb + c_col;
                oB1 = oB0 + 64L * ldb;
            } else {
                oA0 = ((long)(tile_m0 + tt + 1) * 256 + c_r0) * (long)lda + c_col;
                oA1 = oA0 + 64L * lda;
            }
            ST_B0(0, 0); ST_B1(0, 0); ST_A0(0, 0); ST_A1(0, 0);
            ST_B0(1, 1); ST_B1(1, 1); ST_A0(1, 1);
        }

        // ---- epilogue: C/D layout col = lane&15, row = (lane>>4)*4 + jj
        if constexpr (MODE == 0) {
            f16* C = (f16*)Cv + (long)z * sC;
            float p[8][4];
#pragma unroll
            for (int mi = 0; mi < 8; ++mi)
#pragma unroll
                for (int jj = 0; jj < 4; ++jj) p[mi][jj] = 0.f;
#pragma unroll
            for (int mi = 0; mi < 8; ++mi) {
                long r0 = m_base + wm * 128 + mi * 16 + rq * 4;
#pragma unroll
                for (int ni = 0; ni < 4; ++ni) {
                    long c = n_base + wn * 64 + ni * 16 + fr;
#pragma unroll
                    for (int jj = 0; jj < 4; ++jj) {
                        // exp(S/8 - 4) = exp2(acc*scale - 5.77078016),
                        // scale pre-folded with log2(e)
                        float e = exp2f(acc[mi][ni][jj] * scale - 5.77078016f);
                        C[(r0 + jj) * (long)ldc + c] = (f16)e;
                        p[mi][jj] += e;
                    }
                }
            }
            // reduce over the 16 col-lanes sharing each row
#pragma unroll
            for (int mi = 0; mi < 8; ++mi)
#pragma unroll
                for (int jj = 0; jj < 4; ++jj)
#pragma unroll
                    for (int o = 8; o; o >>= 1)
                        p[mi][jj] += __shfl_xor(p[mi][jj], o);
            float* wsum = (float*)(smem + 131072);   // outside the ring
            if (fr == 0) {
#pragma unroll
                for (int mi = 0; mi < 8; ++mi)
#pragma unroll
                    for (int jj = 0; jj < 4; ++jj)
                        wsum[wn * 256 + wm * 128 + mi * 16 + rq * 4 + jj] = p[mi][jj];
            }
            bar();
            if (tid < 256) {
                float s = wsum[tid] + wsum[256 + tid] + wsum[512 + tid] + wsum[768 + tid];
                psum[((long)z * 2048 + m_base + tid) * 8 + (int)(n_base >> 8)] = s;
            }
        } else {
#pragma unroll
            for (int mi = 0; mi < 8; ++mi) {
                long r0 = m_base + wm * 128 + mi * 16 + rq * 4;
#pragma unroll
                for (int ni = 0; ni < 4; ++ni) {
                    long c = n_base + wn * 64 + ni * 16 + fr;
                    if constexpr (MODE == 2) {
                        float* C = (float*)Cv + (long)z * sC;
#pragma unroll
                        for (int jj = 0; jj < 4; ++jj)
                            C[(r0 + jj) * (long)ldc + c] =
                                acc[mi][ni][jj] * dinv[(long)z * 2048 + r0 + jj];
                    } else {  // MODE 4: TV split
                        if (c < 1024) {
                            f16* T = (f16*)Cv;
#pragma unroll
                            for (int jj = 0; jj < 4; ++jj)
                                T[(r0 + jj) * 1024L + c] = (f16)acc[mi][ni][jj];
                        } else {
                            f16* VT = (f16*)((char*)Cv + 67108864);
                            long o = c - 1024;
                            long b = r0 >> 11;
                            long s = r0 & 2047;
                            f16x4 v;
#pragma unroll
                            for (int jj = 0; jj < 4; ++jj) v[jj] = (f16)acc[mi][ni][jj];
                            *(f16x4*)&VT[b * 2097152L + o * 2048L + s] = v;
                        }
                    }
                }
            }
        }

        if (tt + 1 < TILES) {
            WAIT_VM(6);   // FIFO: all K0 loads (oldest) resident; <=6 newest remain
            bar();
        }
    }
#undef ST_A0
#undef ST_A1
#undef ST_B0
#undef ST_B1
}

// ---------------------------------------------------------------------------
// dinv[row] = 1 / sum_{k<8} psum[row*8+k]   (16384 rows)
__global__ __launch_bounds__(256) void reduce_dinv(const float* __restrict__ psum,
                                                   float* __restrict__ dinv) {
    int r = blockIdx.x * 256 + threadIdx.x;
    float4 a = *(const float4*)&psum[(long)r * 8];
    float4 b = *(const float4*)&psum[(long)r * 8 + 4];
    dinv[r] = 1.f / (a.x + a.y + a.z + a.w + b.x + b.y + b.z + b.w);
}

// ---------------------------------------------------------------------------
extern "C" void kernel_launch(void* const* d_in, const int* in_sizes, int n_in,
                              void* d_out, int out_size, void* d_ws, size_t ws_size,
                              hipStream_t stream) {
    const float* x = (const float*)d_in[0];    // [8,2048,1024]
    const float* w = (const float*)d_in[1];    // [3,1024,1024]
    float* out = (float*)d_out;                // [8,2048,1024] f32
    char* ws = (char*)d_ws;

    // workspace layout (bytes), 160 MiB total:
    //   [0,32M)    th: T = x*(WqWk^T)  [16384][1024] f16   (dead after scores)
    //   [32M,64M)  xh: x f16           [16384][1024]       (dead after scores)
    //   [64M,96M)  vt: V^T             [8][1024][2048] f16 (until PV)
    //   [96M,160M) sp: E = exp(S/8-4)  [8][2048][2048] f16
    //     pre-scores this region temporarily holds whq/whk/bTV (all dead
    //     before scores writes sp).
    f16* th  = (f16*)(ws + 0);
    f16* xh  = (f16*)(ws + 33554432);
    f16* vt  = (f16*)(ws + 67108864);
    char* spB = ws + 100663296;
    f16* whq = (f16*)(spB);
    f16* whk = (f16*)(spB + 2097152);
    f16* bTV = (f16*)(spB + 4194304);     // [2048][1024] f16: Mp ; WvT
    f16* sp  = (f16*)(spB);
    float* dinv = (float*)(ws + 0);       // overlays dead th after scores
    float* psum = (float*)d_out;          // 512 KB scratch, overwritten by PV

    // 1) merged prep: x->xh, w[0..1]->whqk flat, w[2]->WvT (one dispatch)
    prep_inputs<<<9472, 256, 0, stream>>>(x, w, xh, whq, bTV + 1048576);

    // 2) Mp[i][j] = sum_o Wk[i][o]*Wq[j][o]  (B-operand rows of (WqWk^T))
    gemm_mp<<<dim3(8, 8), 256, 0, stream>>>(whk, whq, bTV);

    // 3) [T | V^T] = x * [Mp ; WvT]^T — n-TILES=2 (B-panel bTV L2-resident);
    //    RW=4,RH=8 == the validated R9 mapping.
    gemm256<4, 2, 0, 4, 8><<<dim3(4, 64, 1), 512, 131072, stream>>>(
        xh, bTV, ws, nullptr, nullptr, 1024, 1024, 1024, 0L, 0L, 0L, 0, 1.0f);

    // 4) E = exp2(T*x^T*0.18034 - 5.7708) -> sp; fused row sums -> psum.
    //    m-TILES=2, 2x2 XCD rectangles (best measured: R10).
    gemm256<0, 2, 1, 2, 2><<<dim3(8, 4, 8), 512, 135168, stream>>>(
        th, xh, sp, nullptr, psum, 1024, 1024, 1024,
        2097152L, 2097152L, 4194304L, 2048, 0.125f * 1.44269504f);

    // 5) dinv = 1 / rowsum
    reduce_dinv<<<64, 256, 0, stream>>>(psum, dinv);

    // 6) out = (E * V) * dinv — RW=4,RH=1 == the R9 1-D mapping (best measured).
    gemm256<2, 1, 1, 4, 1><<<dim3(4, 8, 8), 512, 131072, stream>>>(
        sp, vt, out, dinv, nullptr, 2048, 2048, 2048,
        4194304L, 2097152L, 2097152L, 1024, 1.0f);
}